// Round 8
// baseline (117.346 us; speedup 1.0000x reference)
//
#include <hip/hip_runtime.h>

// WordSpanLoss: B=16, F=512, T=8192, W=4096, SPACE_TOKEN=63, STRIDE=2
// Single fused kernel: per block derive space positions (hidden under row-0
// cf DMA), prefix-sum span loss over 8 f-rows, last-done block finalizes.

constexpr int SPACE_TOKEN = 63;
constexpr int B = 16;
constexpr int FDIM = 512;
constexpr int T = 8192;
constexpr int W = 4096;
constexpr int ROWS = 8;                   // f-rows per block
constexpr int NBLK = B * FDIM / ROWS;     // 1024 blocks
constexpr int SENT = T;                   // sentinel "position"

__device__ __forceinline__ int swz(int u) { return u ^ ((u >> 3) & 7); }

#define BAR_VM8() do { asm volatile("s_waitcnt vmcnt(8)" ::: "memory"); \
  __builtin_amdgcn_s_barrier(); asm volatile("" ::: "memory"); } while (0)
#define BAR_VM0() do { asm volatile("s_waitcnt vmcnt(0)" ::: "memory"); \
  __builtin_amdgcn_s_barrier(); asm volatile("" ::: "memory"); } while (0)
#define BAR_LGKM() do { asm volatile("s_waitcnt lgkmcnt(0)" ::: "memory"); \
  __builtin_amdgcn_s_barrier(); asm volatile("" ::: "memory"); } while (0)

__device__ __forceinline__ void stage_row(const float4* __restrict__ src,
                                          float* dst, int tid, int wid) {
  float4* d4 = (float4*)dst;
  #pragma unroll
  for (int i = 0; i < 8; ++i) {
    const int u = i * 256 + tid;                 // linear LDS slot
    const float4* gsrc = src + swz(u);           // per-lane swizzled source
    float4* ldst = d4 + (i * 256 + wid * 64);    // wave-uniform base
    __builtin_amdgcn_global_load_lds(
        (const __attribute__((address_space(1))) void*)(const void*)gsrc,
        (__attribute__((address_space(3))) void*)(void*)ldst, 16, 0, 0);
  }
}

__global__ __launch_bounds__(256) void k_fused(
    const float* __restrict__ wp, const float* __restrict__ cf,
    const int* __restrict__ chars, float* __restrict__ partials,
    int* __restrict__ batchValid, unsigned int* __restrict__ counter,
    float* __restrict__ out) {
  const int blk = blockIdx.x;          // 0..NBLK-1
  const int row0 = blk * ROWS;
  const int b = row0 >> 9;             // FDIM = 512
  __shared__ alignas(16) float buf[2][T];       // 64 KB
  __shared__ alignas(16) float csum[256];
  __shared__ alignas(16) float cexc[256];
  __shared__ int posL[260];
  __shared__ int s_wtot[4], s_wpair[4];
  __shared__ float s_red[4];
  __shared__ int s_last;
  __shared__ float f_red[4];
  __shared__ int f_cnt[4];
  const int tid = threadIdx.x;
  const int lane = tid & 63;
  const int wid = tid >> 6;
  const int* cb = chars + (size_t)b * T;

  // --- chars: thread-contiguous int4 loads, issued FIRST (oldest vmcnt) ---
  int4 ch4[8];
  const int4* c4 = (const int4*)cb;
  #pragma unroll
  for (int i = 0; i < 8; ++i) ch4[i] = c4[tid * 8 + i];
  const int nxtAddr = (tid < 255) ? (tid * 32 + 32) : (T - 1);
  int nxt = cb[nxtAddr];               // 9th char load

  // --- row-0 cf DMA (8 newest vmcnt entries per wave) ---
  stage_row((const float4*)(cf + (size_t)row0 * T), buf[0], tid, wid);

  // wait for the 9 char loads only; row-0 DMA (8) stays in flight
  asm volatile("s_waitcnt vmcnt(8)" ::: "memory");
  if (tid == 255) nxt = SPACE_TOKEN + 1;

  posL[tid] = SENT;
  if (tid == 0) { posL[256] = SENT; posL[257] = SENT; posL[258] = SENT; }

  // --- space scan from registers (thread owns chars [tid*32, tid*32+32)) ---
  int cnt = 0, pairs = 0;
  {
    int last = SPACE_TOKEN + 1;
    #pragma unroll
    for (int i = 0; i < 8; ++i) {
      const int4 q = ch4[i];
      cnt += (q.x == SPACE_TOKEN) + (q.y == SPACE_TOKEN) +
             (q.z == SPACE_TOKEN) + (q.w == SPACE_TOKEN);
      pairs += (last == SPACE_TOKEN) && (q.x == SPACE_TOKEN);
      pairs += (q.x == SPACE_TOKEN) && (q.y == SPACE_TOKEN);
      pairs += (q.y == SPACE_TOKEN) && (q.z == SPACE_TOKEN);
      pairs += (q.z == SPACE_TOKEN) && (q.w == SPACE_TOKEN);
      last = q.w;
    }
    pairs += (last == SPACE_TOKEN) && (nxt == SPACE_TOKEN);
  }
  int inc = cnt, pr = pairs;
  #pragma unroll
  for (int o = 1; o < 64; o <<= 1) {
    const int n = __shfl_up(inc, o);
    if (lane >= o) inc += n;
  }
  #pragma unroll
  for (int o = 32; o > 0; o >>= 1) pr += __shfl_down(pr, o);
  if (lane == 63) s_wtot[wid] = inc;
  if (lane == 0) s_wpair[wid] = pr;
  BAR_LGKM();   // posL init + s_wtot/s_wpair visible

  int wexc = 0;
  for (int w = 0; w < wid; ++w) wexc += s_wtot[w];
  const int S = s_wtot[0] + s_wtot[1] + s_wtot[2] + s_wtot[3];
  const int P = s_wpair[0] + s_wpair[1] + s_wpair[2] + s_wpair[3];
  int rk = wexc + inc - cnt;           // exclusive rank of thread's 1st space
  #pragma unroll
  for (int i = 0; i < 8; ++i) {
    const int4 q = ch4[i];
    const int t0 = tid * 32 + i * 4;
    if (q.x == SPACE_TOKEN) { if (rk < 258) posL[rk] = t0 + 0; ++rk; }
    if (q.y == SPACE_TOKEN) { if (rk < 258) posL[rk] = t0 + 1; ++rk; }
    if (q.z == SPACE_TOKEN) { if (rk < 258) posL[rk] = t0 + 2; ++rk; }
    if (q.w == SPACE_TOKEN) { if (rk < 258) posL[rk] = t0 + 3; ++rk; }
  }
  BAR_LGKM();   // posL scatter visible

  // --- per-thread span registers + wp prefetch (8 named scalars) ---
  const int p0r = posL[tid];
  const int p1r = posL[tid + 1];
  const int gidx = (p0r >> 1) & (W - 1);        // safe for sentinel
  const float* wpb = wp + (size_t)row0 * W + gidx;
  const float wv0 = wpb[0 * W];
  const float wv1 = wpb[1 * W];
  const float wv2 = wpb[2 * W];
  const float wv3 = wpb[3 * W];
  const float wv4 = wpb[4 * W];
  const float wv5 = wpb[5 * W];
  const float wv6 = wpb[6 * W];
  const float wv7 = wpb[7 * W];

  float acc = 0.f;
  #pragma unroll 1
  for (int r = 0; r < ROWS; ++r) {
    if (r + 1 < ROWS)
      stage_row((const float4*)(cf + (size_t)(row0 + r + 1) * T),
                buf[(r + 1) & 1], tid, wid);
    // drains row r (+ wp prefetch at r=0); row r+1's 8 DMA stay in flight
    if (r + 1 < ROWS) { BAR_VM8(); } else { BAR_VM0(); }

    float* rowf = buf[r & 1];
    float4* r4 = (float4*)rowf;

    // phase b: per-thread 32-float in-register inclusive prefix
    float4 v[8];
    #pragma unroll
    for (int i = 0; i < 8; ++i) v[i] = r4[swz(tid * 8 + i)];
    float run = 0.f;
    #pragma unroll
    for (int i = 0; i < 8; ++i) {
      v[i].x = (run += v[i].x);
      v[i].y = (run += v[i].y);
      v[i].z = (run += v[i].z);
      v[i].w = (run += v[i].w);
    }
    #pragma unroll
    for (int i = 0; i < 8; ++i) r4[swz(tid * 8 + i)] = v[i];
    csum[tid] = run;
    BAR_LGKM();

    // phase c: wave 0 scans 256 chunk totals -> exclusive offsets
    if (tid < 64) {
      const float4 sv = ((const float4*)csum)[tid];
      const float l1 = sv.x + sv.y;
      const float l2 = l1 + sv.z;
      const float tot = l2 + sv.w;
      float pinc = tot;
      #pragma unroll
      for (int o = 1; o < 64; o <<= 1) {
        const float n = __shfl_up(pinc, o);
        if (tid >= o) pinc += n;
      }
      const float exc = pinc - tot;
      ((float4*)cexc)[tid] = make_float4(exc, exc + sv.x, exc + l1, exc + l2);
    }
    BAR_LGKM();

    // phase d: span evaluation from registers + LDS
    if (tid < S - 1) {
      const int scnt = p1r - p0r - 1;
      if (scnt > 0) {
        const int ta = p1r - 1;
        const float Pa = rowf[(swz(ta >> 2) << 2) | (ta & 3)] + cexc[ta >> 5];
        const float Pb = rowf[(swz(p0r >> 2) << 2) | (p0r & 3)] + cexc[p0r >> 5];
        const float mean = (Pa - Pb) / (float)scnt;
        const float wvr = (r == 0) ? wv0 : (r == 1) ? wv1 : (r == 2) ? wv2 :
                          (r == 3) ? wv3 : (r == 4) ? wv4 : (r == 5) ? wv5 :
                          (r == 6) ? wv6 : wv7;
        const float d = wvr - mean;
        acc += d * d;
      }
    }
    // correctness tail (S-1 > 256, never hit at bench stats)
    if (S - 1 > 256) {
      int want = 256 + tid;
      if (want < S - 1) {
        int rank2 = 0;
        int p0 = -1;
        for (int t = 0; t < T; ++t) {
          if (cb[t] == SPACE_TOKEN) {
            if (rank2 == want) {
              p0 = t;
            } else if (rank2 == want + 1) {
              const int scnt = t - p0 - 1;
              if (scnt > 0) {
                const int ta = t - 1;
                const float Pa = rowf[(swz(ta >> 2) << 2) | (ta & 3)] + cexc[ta >> 5];
                const float Pb = rowf[(swz(p0 >> 2) << 2) | (p0 & 3)] + cexc[p0 >> 5];
                const float mean = (Pa - Pb) / (float)scnt;
                const float d = wp[(size_t)(row0 + r) * W + (p0 >> 1)] - mean;
                acc += d * d;
              }
              want += 256;
              if (want >= S - 1) break;
            }
            rank2++;
          }
        }
      }
    }
    BAR_LGKM();   // protect buf[r&1] before next iteration's DMA overwrite
  }

  // --- block reduction -> partial; last-done block finalizes ---
  #pragma unroll
  for (int o = 32; o > 0; o >>= 1) acc += __shfl_down(acc, o);
  if (lane == 0) s_red[wid] = acc;
  __syncthreads();
  if (tid == 0) {
    partials[blk] = s_red[0] + s_red[1] + s_red[2] + s_red[3];
    if ((blk & 63) == 0) batchValid[b] = (S > 1 ? S - 1 : 0) - P;
    __threadfence();                       // publish before arrival
    const unsigned int old = atomicAdd(counter, 1u);
    s_last = (old == (unsigned int)(NBLK - 1)) ? 1 : 0;
  }
  __syncthreads();
  if (s_last) {
    __threadfence();                       // acquire all blocks' writes
    float s = 0.f;
    for (int i = tid; i < NBLK; i += 256) s += partials[i];
    int c2 = 0;
    for (int i = tid; i < B; i += 256) c2 += batchValid[i];
    for (int o = 32; o > 0; o >>= 1) {
      s += __shfl_down(s, o);
      c2 += __shfl_down(c2, o);
    }
    if (lane == 0) { f_red[wid] = s; f_cnt[wid] = c2; }
    __syncthreads();
    if (tid == 0) {
      const float total = f_red[0] + f_red[1] + f_red[2] + f_red[3];
      const int c = f_cnt[0] + f_cnt[1] + f_cnt[2] + f_cnt[3];
      out[0] = (c > 0) ? total / ((float)FDIM * (float)c) : 0.f;
    }
  }
}

extern "C" void kernel_launch(void* const* d_in, const int* in_sizes, int n_in,
                              void* d_out, int out_size, void* d_ws, size_t ws_size,
                              hipStream_t stream) {
  const float* wp = (const float*)d_in[0];
  const float* cf = (const float*)d_in[1];
  const int* chars = (const int*)d_in[2];
  float* out = (float*)d_out;

  char* ws = (char*)d_ws;
  float* partials = (float*)ws;                        // NBLK floats
  int* batchValid = (int*)(ws + NBLK * 4);             // B ints
  unsigned int* counter = (unsigned int*)(ws + NBLK * 4 + B * 4);

  hipMemsetAsync(counter, 0, 4, stream);
  k_fused<<<NBLK, 256, 0, stream>>>(wp, cf, chars, partials, batchValid,
                                    counter, out);
}

// Round 9
// 71.658 us; speedup vs baseline: 1.6376x; 1.6376x over previous
//
#include <hip/hip_runtime.h>

// WordSpanLoss: B=16, F=512, T=8192, W=4096, SPACE_TOKEN=63, STRIDE=2
// Two kernels. k_fused: per block (8 f-rows of one batch) derive space
// positions (hidden under first DMA), then per row: half-row (16 KB) staged
// prefix-sum span loss. 36 KB LDS -> 4 blocks/CU for latency hiding.
// Cross-half spans: Pb stashed in a register during half 0 (+ carry).

constexpr int SPACE_TOKEN = 63;
constexpr int B = 16;
constexpr int FDIM = 512;
constexpr int T = 8192;
constexpr int W = 4096;
constexpr int ROWS = 8;                   // f-rows per block
constexpr int NBLK = B * FDIM / ROWS;     // 1024 blocks
constexpr int HALF = 4096;                // floats per staged half-row
constexpr int SENT = T;                   // sentinel "position"

__device__ __forceinline__ int swz(int u) { return u ^ ((u >> 3) & 7); }

#define BAR_VM4() do { asm volatile("s_waitcnt vmcnt(4)" ::: "memory"); \
  __builtin_amdgcn_s_barrier(); asm volatile("" ::: "memory"); } while (0)
#define BAR_VM0() do { asm volatile("s_waitcnt vmcnt(0)" ::: "memory"); \
  __builtin_amdgcn_s_barrier(); asm volatile("" ::: "memory"); } while (0)
#define BAR_LGKM() do { asm volatile("s_waitcnt lgkmcnt(0)" ::: "memory"); \
  __builtin_amdgcn_s_barrier(); asm volatile("" ::: "memory"); } while (0)

// stage one 16-KB half-row: 4 global_load_lds per wave, linear LDS dest,
// pre-swizzled per-lane source (swz is an involution; slot swz(u) <- src[u])
__device__ __forceinline__ void stage_half(const float4* __restrict__ src,
                                           float* dst, int tid, int wid) {
  float4* d4 = (float4*)dst;
  #pragma unroll
  for (int i = 0; i < 4; ++i) {
    const int u = i * 256 + tid;                 // linear LDS float4 slot
    const float4* gsrc = src + swz(u);
    float4* ldst = d4 + (i * 256 + wid * 64);    // wave-uniform base
    __builtin_amdgcn_global_load_lds(
        (const __attribute__((address_space(1))) void*)(const void*)gsrc,
        (__attribute__((address_space(3))) void*)(void*)ldst, 16, 0, 0);
  }
}

__global__ __launch_bounds__(256, 4) void k_fused(
    const float* __restrict__ wp, const float* __restrict__ cf,
    const int* __restrict__ chars, float* __restrict__ partials,
    int* __restrict__ batchValid) {
  const int blk = blockIdx.x;          // 0..NBLK-1
  const int row0 = blk * ROWS;
  const int b = row0 >> 9;             // FDIM = 512
  __shared__ alignas(16) float buf0[HALF];      // even halves (16 KB)
  __shared__ alignas(16) float buf1[HALF];      // odd halves  (16 KB)
  __shared__ alignas(16) float csum[256];
  __shared__ alignas(16) float cexc[256];
  __shared__ int posL[260];
  __shared__ int s_wtot[4], s_wpair[4];
  __shared__ float s_red[4];
  __shared__ float s_carry;
  const int tid = threadIdx.x;
  const int lane = tid & 63;
  const int wid = tid >> 6;
  const int* cb = chars + (size_t)b * T;

  // --- chars: 9 loads issued FIRST (oldest in vmcnt) ---
  int4 ch4[8];
  const int4* c4 = (const int4*)cb;
  #pragma unroll
  for (int i = 0; i < 8; ++i) ch4[i] = c4[tid * 8 + i];
  const int nxtAddr = (tid < 255) ? (tid * 32 + 32) : (T - 1);
  int nxt = cb[nxtAddr];

  // --- half 0 of row 0 (4 newest vmcnt entries per wave) ---
  stage_half((const float4*)(cf + (size_t)row0 * T), buf0, tid, wid);

  // wait for the 9 char loads; half-0 DMA (4) stays in flight
  asm volatile("s_waitcnt vmcnt(4)" ::: "memory");
  if (tid == 255) nxt = SPACE_TOKEN + 1;

  posL[tid] = SENT;
  if (tid == 0) { posL[256] = SENT; posL[257] = SENT; posL[258] = SENT; }

  // --- space scan from registers (thread owns chars [tid*32, tid*32+32)) ---
  int cnt = 0, pairs = 0;
  {
    int last = SPACE_TOKEN + 1;
    #pragma unroll
    for (int i = 0; i < 8; ++i) {
      const int4 q = ch4[i];
      cnt += (q.x == SPACE_TOKEN) + (q.y == SPACE_TOKEN) +
             (q.z == SPACE_TOKEN) + (q.w == SPACE_TOKEN);
      pairs += (last == SPACE_TOKEN) && (q.x == SPACE_TOKEN);
      pairs += (q.x == SPACE_TOKEN) && (q.y == SPACE_TOKEN);
      pairs += (q.y == SPACE_TOKEN) && (q.z == SPACE_TOKEN);
      pairs += (q.z == SPACE_TOKEN) && (q.w == SPACE_TOKEN);
      last = q.w;
    }
    pairs += (last == SPACE_TOKEN) && (nxt == SPACE_TOKEN);
  }
  int inc = cnt, pr = pairs;
  #pragma unroll
  for (int o = 1; o < 64; o <<= 1) {
    const int n = __shfl_up(inc, o);
    if (lane >= o) inc += n;
  }
  #pragma unroll
  for (int o = 32; o > 0; o >>= 1) pr += __shfl_down(pr, o);
  if (lane == 63) s_wtot[wid] = inc;
  if (lane == 0) s_wpair[wid] = pr;
  BAR_LGKM();

  int wexc = 0;
  for (int w = 0; w < wid; ++w) wexc += s_wtot[w];
  const int S = s_wtot[0] + s_wtot[1] + s_wtot[2] + s_wtot[3];
  const int P = s_wpair[0] + s_wpair[1] + s_wpair[2] + s_wpair[3];
  int rk = wexc + inc - cnt;
  #pragma unroll
  for (int i = 0; i < 8; ++i) {
    const int4 q = ch4[i];
    const int t0 = tid * 32 + i * 4;
    if (q.x == SPACE_TOKEN) { if (rk < 258) posL[rk] = t0 + 0; ++rk; }
    if (q.y == SPACE_TOKEN) { if (rk < 258) posL[rk] = t0 + 1; ++rk; }
    if (q.z == SPACE_TOKEN) { if (rk < 258) posL[rk] = t0 + 2; ++rk; }
    if (q.w == SPACE_TOKEN) { if (rk < 258) posL[rk] = t0 + 3; ++rk; }
  }
  BAR_LGKM();

  if ((blk & 63) == 0 && tid == 0)
    batchValid[b] = (S > 1 ? S - 1 : 0) - P;

  // --- per-thread span registers + wp prefetch (8 named scalars) ---
  const int p0r = posL[tid];
  const int p1r = posL[tid + 1];
  const int gidx = (p0r >> 1) & (W - 1);        // safe for sentinel
  const float* wpb = wp + (size_t)row0 * W + gidx;
  const float wv0 = wpb[0 * W];
  const float wv1 = wpb[1 * W];
  const float wv2 = wpb[2 * W];
  const float wv3 = wpb[3 * W];
  const float wv4 = wpb[4 * W];
  const float wv5 = wpb[5 * W];
  const float wv6 = wpb[6 * W];
  const float wv7 = wpb[7 * W];

  const bool spanOk = (tid < S - 1) && (p1r - p0r - 1 > 0);
  const int scnt = p1r - p0r - 1;
  const int ta = p1r - 1;

  float Pb_st = 0.f, rcarry = 0.f, acc = 0.f;

  #pragma unroll 1
  for (int r = 0; r < ROWS; ++r) {
    const float wvr = (r == 0) ? wv0 : (r == 1) ? wv1 : (r == 2) ? wv2 :
                      (r == 3) ? wv3 : (r == 4) ? wv4 : (r == 5) ? wv5 :
                      (r == 6) ? wv6 : wv7;
    const float* crow = cf + (size_t)(row0 + r) * T;

    // ================= half 0 (buf0) =================
    // stage half 1 of this row (stays in flight across barriers)
    stage_half((const float4*)(crow + HALF), buf1, tid, wid);
    BAR_VM4();   // drains half 0 (+ wp/char prefetches at r=0)

    {
      float4* r4 = (float4*)buf0;
      float4 v[4];
      #pragma unroll
      for (int i = 0; i < 4; ++i) v[i] = r4[swz(tid * 4 + i)];
      float run = 0.f;
      #pragma unroll
      for (int i = 0; i < 4; ++i) {
        v[i].x = (run += v[i].x);
        v[i].y = (run += v[i].y);
        v[i].z = (run += v[i].z);
        v[i].w = (run += v[i].w);
      }
      #pragma unroll
      for (int i = 0; i < 4; ++i) r4[swz(tid * 4 + i)] = v[i];
      csum[tid] = run;
    }
    BAR_LGKM();
    if (tid < 64) {
      const float4 sv = ((const float4*)csum)[tid];
      const float l1 = sv.x + sv.y;
      const float l2 = l1 + sv.z;
      const float tot = l2 + sv.w;
      float pinc = tot;
      #pragma unroll
      for (int o = 1; o < 64; o <<= 1) {
        const float n = __shfl_up(pinc, o);
        if (tid >= o) pinc += n;
      }
      const float exc = pinc - tot;
      ((float4*)cexc)[tid] = make_float4(exc, exc + sv.x, exc + l1, exc + l2);
      if (tid == 63) s_carry = pinc;
    }
    BAR_LGKM();
    rcarry = s_carry;                 // total of half 0 (carry for half 1)
    if (spanOk) {
      if (p0r < HALF)
        Pb_st = buf0[(swz(p0r >> 2) << 2) | (p0r & 3)] + cexc[p0r >> 4];
      if (ta < HALF) {
        const float Pa = buf0[(swz(ta >> 2) << 2) | (ta & 3)] + cexc[ta >> 4];
        const float mean = (Pa - Pb_st) / (float)scnt;
        const float d = wvr - mean;
        acc += d * d;
      }
    }
    BAR_LGKM();  // buf0 reads done before restage below; cexc reads done

    // ================= half 1 (buf1) =================
    if (r + 1 < ROWS)   // stage half 0 of next row
      stage_half((const float4*)(cf + (size_t)(row0 + r + 1) * T), buf0,
                 tid, wid);
    if (r + 1 < ROWS) { BAR_VM4(); } else { BAR_VM0(); }  // drains half 1

    {
      float4* r4 = (float4*)buf1;
      float4 v[4];
      #pragma unroll
      for (int i = 0; i < 4; ++i) v[i] = r4[swz(tid * 4 + i)];
      float run = 0.f;
      #pragma unroll
      for (int i = 0; i < 4; ++i) {
        v[i].x = (run += v[i].x);
        v[i].y = (run += v[i].y);
        v[i].z = (run += v[i].z);
        v[i].w = (run += v[i].w);
      }
      #pragma unroll
      for (int i = 0; i < 4; ++i) r4[swz(tid * 4 + i)] = v[i];
      csum[tid] = run;
    }
    BAR_LGKM();
    if (tid < 64) {
      const float4 sv = ((const float4*)csum)[tid];
      const float l1 = sv.x + sv.y;
      const float l2 = l1 + sv.z;
      const float tot = l2 + sv.w;
      float pinc = tot;
      #pragma unroll
      for (int o = 1; o < 64; o <<= 1) {
        const float n = __shfl_up(pinc, o);
        if (tid >= o) pinc += n;
      }
      const float exc = pinc - tot;
      ((float4*)cexc)[tid] = make_float4(exc, exc + sv.x, exc + l1, exc + l2);
    }
    BAR_LGKM();
    if (spanOk && ta >= HALF) {
      const int tb = ta - HALF;
      const float Pa = buf1[(swz(tb >> 2) << 2) | (tb & 3)] + cexc[tb >> 4]
                       + rcarry;
      float Pb;
      if (p0r < HALF) {
        Pb = Pb_st;
      } else {
        const int pb = p0r - HALF;
        Pb = buf1[(swz(pb >> 2) << 2) | (pb & 3)] + cexc[pb >> 4] + rcarry;
      }
      const float mean = (Pa - Pb) / (float)scnt;
      const float d = wvr - mean;
      acc += d * d;
    }
    // correctness tail (S-1 > 256, never hit at bench stats): global direct
    if (S - 1 > 256) {
      int want = 256 + tid;
      if (want < S - 1) {
        int rank2 = 0;
        int p0 = -1;
        for (int t = 0; t < T; ++t) {
          if (cb[t] == SPACE_TOKEN) {
            if (rank2 == want) {
              p0 = t;
            } else if (rank2 == want + 1) {
              const int sc = t - p0 - 1;
              if (sc > 0) {
                float ssum = 0.f;
                for (int u = p0 + 1; u < t; ++u) ssum += crow[u];
                const float mean = ssum / (float)sc;
                const float d = wp[(size_t)(row0 + r) * W + (p0 >> 1)] - mean;
                acc += d * d;
              }
              want += 256;
              if (want >= S - 1) break;
            }
            rank2++;
          }
        }
      }
    }
    BAR_LGKM();  // buf1/cexc reads done before next row's half-1 stage
  }

  // --- block reduction -> one partial per block ---
  #pragma unroll
  for (int o = 32; o > 0; o >>= 1) acc += __shfl_down(acc, o);
  if (lane == 0) s_red[wid] = acc;
  __syncthreads();
  if (tid == 0) partials[blk] = s_red[0] + s_red[1] + s_red[2] + s_red[3];
}

// ---------------- kernel 2: deterministic final reduction ----------------
__global__ __launch_bounds__(256) void k_finalize(
    const float* __restrict__ partials, const int* __restrict__ batchValid,
    float* __restrict__ out) {
  __shared__ float s_red[4];
  __shared__ int s_cnt[4];
  const int tid = threadIdx.x;
  const int lane = tid & 63;
  const int wid = tid >> 6;
  float s = 0.f;
  for (int i = tid; i < NBLK; i += 256) s += partials[i];
  int cnt = 0;
  for (int i = tid; i < B; i += 256) cnt += batchValid[i];
  for (int o = 32; o > 0; o >>= 1) {
    s += __shfl_down(s, o);
    cnt += __shfl_down(cnt, o);
  }
  if (lane == 0) { s_red[wid] = s; s_cnt[wid] = cnt; }
  __syncthreads();
  if (tid == 0) {
    const float total = s_red[0] + s_red[1] + s_red[2] + s_red[3];
    const int c = s_cnt[0] + s_cnt[1] + s_cnt[2] + s_cnt[3];
    out[0] = (c > 0) ? total / ((float)FDIM * (float)c) : 0.f;
  }
}

extern "C" void kernel_launch(void* const* d_in, const int* in_sizes, int n_in,
                              void* d_out, int out_size, void* d_ws, size_t ws_size,
                              hipStream_t stream) {
  const float* wp = (const float*)d_in[0];
  const float* cf = (const float*)d_in[1];
  const int* chars = (const int*)d_in[2];
  float* out = (float*)d_out;

  char* ws = (char*)d_ws;
  float* partials = (float*)ws;                 // NBLK floats
  int* batchValid = (int*)(ws + NBLK * 4);      // B ints

  k_fused<<<NBLK, 256, 0, stream>>>(wp, cf, chars, partials, batchValid);
  k_finalize<<<1, 256, 0, stream>>>(partials, batchValid, out);
}